// Round 12
// baseline (366.132 us; speedup 1.0000x reference)
//
#include <hip/hip_runtime.h>
#include <hip/hip_bf16.h>

typedef unsigned char u8;
typedef unsigned short u16;
typedef unsigned int u32;
typedef int i32x8 __attribute__((ext_vector_type(8)));
typedef float f32x4 __attribute__((ext_vector_type(4)));

#define NX 8192
#define NY 8192
#define D  512
#define BM 128
#define BN 128
#define BK 128          // fp8 bytes per K-step; one 16x16x128 MFMA spans it
#define NKT 4           // K-steps (D/BK)
#define TPB 16          // tiles per block (along one stripe)

#define SCALE_ONE 0x7F7F7F7F  // E8M0 127 = 2^0 in every byte -> any opsel picks 1.0

// async global->LDS, 16B per lane. LDS dst is wave-uniform base + lane*16.
__device__ __forceinline__ void async16(void* lds, const void* g) {
    __builtin_amdgcn_global_load_lds(
        (const __attribute__((address_space(1))) void*)g,
        (__attribute__((address_space(3))) void*)lds,
        16, 0, 0);
}

// One WAVE per row (16384 rows: first 8192 = x, rest = y). No LDS, no barrier.
// fp32 -> fp8 e4m3 (HW cvt) into ws + exact fp32 squared row norm.
__global__ __launch_bounds__(256) void prep_kernel(
    const float* __restrict__ x, const float* __restrict__ y,
    u8* __restrict__ xq, u8* __restrict__ yq,
    float* __restrict__ x2, float* __restrict__ y2)
{
    const int lane = threadIdx.x & 63;
    const int row  = blockIdx.x * 4 + (threadIdx.x >> 6);
    const float* src; u8* dst; float* nrm;
    if (row < NX) {
        src = x + (size_t)row * D; dst = xq + (size_t)row * D; nrm = x2 + row;
    } else {
        const int r = row - NX;
        src = y + (size_t)r * D; dst = yq + (size_t)r * D; nrm = y2 + r;
    }
    float4 v0 = *(const float4*)(src + lane * 8);
    float4 v1 = *(const float4*)(src + lane * 8 + 4);
    float s = v0.x*v0.x + v0.y*v0.y + v0.z*v0.z + v0.w*v0.w
            + v1.x*v1.x + v1.y*v1.y + v1.z*v1.z + v1.w*v1.w;
    u32 p0 = 0, p1 = 0;
    p0 = __builtin_amdgcn_cvt_pk_fp8_f32(v0.x, v0.y, p0, false);
    p0 = __builtin_amdgcn_cvt_pk_fp8_f32(v0.z, v0.w, p0, true);
    p1 = __builtin_amdgcn_cvt_pk_fp8_f32(v1.x, v1.y, p1, false);
    p1 = __builtin_amdgcn_cvt_pk_fp8_f32(v1.z, v1.w, p1, true);
    uint2 pk = make_uint2(p0, p1);
    *(uint2*)(dst + lane * 8) = pk;

    #pragma unroll
    for (int o = 32; o > 0; o >>= 1) s += __shfl_down(s, o);
    if (lane == 0) *nrm = s;
}

// Persistent-stripe RBF GEMM. 256 blocks, 1/CU (96 KB LDS). Block (brow, bg)
// owns stripe rows [brow*128, +128) x 16 tiles of 128 cols (bg*2048 + tt*128).
// A panel (128 x 512 fp8 = 64 KB, chunked per K-step) staged ONCE; B tiles
// streamed double-buffered (2 x 16 KB). Inner k-step code identical to the
// measured R9 kernel (same layouts, fragments, mfma_scale, epilogue).
// Stores are fire-and-forget: vmcnt releases on L2 ack at the next barrier;
// L2->HBM dirty drain of tile t overlaps tile t+1's compute, keeping the
// write port continuously busy (vs phase-aligned bursts of short-lived blocks).
__global__ __launch_bounds__(256) void rbf_kernel(
    const u8* __restrict__ xq, const u8* __restrict__ yq,
    const float* __restrict__ x2, const float* __restrict__ y2,
    const float* __restrict__ gamma_p, float* __restrict__ out)
{
    __shared__ u8 Al[NKT * BM * BK];   // 64 KiB: full-K A panel, [kt][128][128]
    __shared__ u8 Bl[2][BN * BK];      // 2 x 16 KiB: B tile double buffer

    const int t    = threadIdx.x;
    const int lane = t & 63;
    const int wid  = t >> 6;          // 0..3
    const int wr   = wid >> 1;        // row half
    const int wc   = wid & 1;         // col half

    const int bid  = blockIdx.x;      // 256 blocks = 64 brow x 4 bg
    const int brow = bid >> 2;
    const int bg   = bid & 3;

    const size_t row0 = (size_t)brow * BM;

    // chunk geometry (identical to R9): 1024 B = 8 rows x 128 B; lane covers
    // 16 B at row += lane>>3, colbyte = (lane&7)*16.
    const int lr = lane >> 3;
    const int lc = (lane & 7) * 16;

    // ---- prologue: stage full A panel (64 chunks; 16 per wave) + B(t0,k0) ----
    #pragma unroll
    for (int i = 0; i < 16; ++i) {
        const int c  = wid * 16 + i;       // 0..63
        const int kt = c >> 4;             // K-step chunk group
        const int cc = c & 15;             // row-chunk within K-step
        async16(&Al[c * 1024],
                xq + (row0 + (size_t)(cc * 8 + lr)) * D + kt * BK + lc);
    }
    {   // B for (tile 0, kstep 0)
        const size_t col0 = (size_t)(bg * 16 + 0) * BN;
        #pragma unroll
        for (int i = 0; i < 4; ++i) {
            const int c = wid * 4 + i;     // 0..15
            async16(&Bl[0][c * 1024],
                    yq + (col0 + (size_t)(c * 8 + lr)) * D + 0 * BK + lc);
        }
    }
    __syncthreads();   // drain: A panel + first B tile-chunk resident

    const float gamma = *gamma_p;
    const int ko = (lane >> 4) * 32;
    const int ar = (lane & 15);
    const int rl = (lane >> 4) * 4;   // C/D: row = (lane>>4)*4 + reg, col = lane&15
    const int cl = lane & 15;

    int cur = 0;
    for (int tt = 0; tt < TPB; ++tt) {
        f32x4 acc[4][4] = {};
        #pragma unroll
        for (int kt = 0; kt < NKT; ++kt) {
            // prefetch next B chunk (next kstep, or next tile's kstep 0)
            const int nchunk = tt * NKT + kt + 1;
            if (nchunk < TPB * NKT) {
                const int ntt = nchunk >> 2;
                const int nkt = nchunk & 3;
                const size_t ncol0 = (size_t)(bg * 16 + ntt) * BN;
                #pragma unroll
                for (int i = 0; i < 4; ++i) {
                    const int c = wid * 4 + i;
                    async16(&Bl[cur ^ 1][c * 1024],
                            yq + (ncol0 + (size_t)(c * 8 + lr)) * D + nkt * BK + lc);
                }
            }
            // compute from Al[kt], Bl[cur]  (identical to R9 inner step)
            i32x8 a[4], b[4];
            #pragma unroll
            for (int m = 0; m < 4; ++m)
                a[m] = *(const i32x8*)&Al[kt * (BM * BK) + (wr * 64 + m * 16 + ar) * BK + ko];
            #pragma unroll
            for (int n = 0; n < 4; ++n)
                b[n] = *(const i32x8*)&Bl[cur][(wc * 64 + n * 16 + ar) * BK + ko];
            #pragma unroll
            for (int m = 0; m < 4; ++m)
                #pragma unroll
                for (int n = 0; n < 4; ++n)
                    acc[m][n] = __builtin_amdgcn_mfma_scale_f32_16x16x128_f8f6f4(
                        a[m], b[n], acc[m][n],
                        0 /*A=fp8*/, 0 /*B=fp8*/,
                        0, SCALE_ONE, 0, SCALE_ONE);
            __syncthreads();   // prefetch landed; reads of cur done; stores acked
            cur ^= 1;
        }

        // epilogue for tile tt: fire-and-forget stores (no barrier after)
        const size_t col0 = (size_t)(bg * 16 + tt) * BN;
        #pragma unroll
        for (int m = 0; m < 4; ++m) {
            #pragma unroll
            for (int j = 0; j < 4; ++j) {
                const size_t gr = row0 + wr * 64 + m * 16 + rl + j;
                const float xn = x2[gr];
                float* orow = out + gr * (size_t)NY + col0 + wc * 64 + cl;
                #pragma unroll
                for (int n = 0; n < 4; ++n) {
                    const float yn = y2[col0 + wc * 64 + n * 16 + cl];
                    float sq = xn + yn - 2.0f * acc[m][n][j];
                    sq = fmaxf(sq, 0.0f);
                    orow[n * 16] = __expf(-gamma * sq);
                }
            }
        }
    }
}

extern "C" void kernel_launch(void* const* d_in, const int* in_sizes, int n_in,
                              void* d_out, int out_size, void* d_ws, size_t ws_size,
                              hipStream_t stream) {
    const float* x = (const float*)d_in[0];
    const float* y = (const float*)d_in[1];
    const float* gamma_p = (const float*)d_in[2];
    float* out = (float*)d_out;

    // ws layout: xq[8192*512] u8 | yq[8192*512] u8 | x2[8192] f32 | y2[8192] f32
    u8* xq = (u8*)d_ws;
    u8* yq = xq + (size_t)NX * D;
    float* x2 = (float*)(yq + (size_t)NY * D);
    float* y2 = x2 + NX;

    prep_kernel<<<(NX + NY) / 4, 256, 0, stream>>>(x, y, xq, yq, x2, y2);

    // 256 persistent blocks: 64 stripes x 4 col-groups, 1 block/CU (96 KB LDS)
    rbf_kernel<<<256, 256, 0, stream>>>(xq, yq, x2, y2, gamma_p, out);
}